// Round 8
// baseline (238.950 us; speedup 1.0000x reference)
//
#include <hip/hip_runtime.h>
#include <hip/hip_fp16.h>
#include <math.h>

// Problem constants
#define BB   2
#define CSN  128
#define CDN  128
#define SD   8
#define SH   16
#define SW   16
#define DD   16
#define DH   32
#define DW   32
#define PP   (DD*DH*DW)   // 16384
#define GG   8
#define K3   27
#define OO   648

typedef _Float16 half8 __attribute__((ext_vector_type(8)));
typedef float f32x4 __attribute__((ext_vector_type(4)));
typedef __attribute__((address_space(1))) const float4 gf4;
typedef __attribute__((address_space(3))) float4 sf4;

// ---------------------------------------------------------------------------
// Kernel 1: PREP — upsample + weight packs (R16 version, unrolled out-loop).
// ---------------------------------------------------------------------------
__global__ __launch_bounds__(256) void prep_kernel(
    const float* __restrict__ src, const float* __restrict__ wof,
    const float* __restrict__ wdcn, half8* __restrict__ uph8,
    half8* __restrict__ woxg, half8* __restrict__ wtx2)
{
    __shared__ float slab[2 * 8 * 16 * 17];
    const int bid = blockIdx.x;
    const int tid = threadIdx.x;

    if (bid < 512) {
        const int zo = bid & 15, pl = bid >> 4;
        const int h = pl & 1, g = (pl >> 1) & 7, b = pl >> 4;
        const int z0 = (zo - 1) >> 1;
        const float fz = (zo & 1) ? 0.25f : 0.75f;
        {
            const int zi = tid >> 7, cc = (tid >> 4) & 7, y = tid & 15;
            const int zsrc = min(max(z0 + zi, 0), SD - 1);
            const float* srow = src +
                (((size_t)(b * CSN + g * 16 + h * 8 + cc) * SD + zsrc) * SH + y) * SW;
            float* drow = &slab[((zi * 8 + cc) * 16 + y) * 17];
            *(float4*)(drow)      = *(const float4*)(srow);
            *(float4*)(drow + 4)  = *(const float4*)(srow + 4);
            *(float4*)(drow + 8)  = *(const float4*)(srow + 8);
            *(float4*)(drow + 12) = *(const float4*)(srow + 12);
        }
        __syncthreads();

        const float wz0 = 1.f - fz, wz1 = fz;
#pragma unroll
        for (int i = 0; i < 4; ++i) {
            const int pp = tid + i * 256;
            const int yo = pp >> 5, xo = pp & 31;
            const int y0 = (yo - 1) >> 1;
            const float fy = (yo & 1) ? 0.25f : 0.75f;
            const int ys0 = max(y0, 0), ys1 = min(y0 + 1, SH - 1);
            const int x0 = (xo - 1) >> 1;
            const float fx = (xo & 1) ? 0.25f : 0.75f;
            const int xs0 = max(x0, 0), xs1 = min(x0 + 1, SW - 1);
            const float w00 = (1.f - fy) * (1.f - fx), w01 = (1.f - fy) * fx;
            const float w10 = fy * (1.f - fx),         w11 = fy * fx;
            const int a00 = ys0 * 17 + xs0, a01 = ys0 * 17 + xs1;
            const int a10 = ys1 * 17 + xs0, a11 = ys1 * 17 + xs1;

            half8 hv;
#pragma unroll
            for (int cc = 0; cc < 8; ++cc) {
                const float* pa = &slab[(cc * 16) * 17];
                const float* pb = &slab[((8 + cc) * 16) * 17];
                const float s0 = w00 * pa[a00] + w01 * pa[a01]
                               + w10 * pa[a10] + w11 * pa[a11];
                const float s1 = w00 * pb[a00] + w01 * pb[a01]
                               + w10 * pb[a10] + w11 * pb[a11];
                hv[cc] = (_Float16)(wz0 * s0 + wz1 * s1);
            }
            uph8[(size_t)pl * PP + zo * 1024 + pp] = hv;
        }
    } else if (bid < 608) {
        const int i = (bid - 512) * 256 + tid;     // < 24576
        const int q = i & 3, lo = (i >> 2) & 15;
        const int t6 = i >> 6;
        const int ot = t6 % 6;
        const int gc0 = t6 / 6;
        const int c0 = gc0 & 7, g = gc0 >> 3;
        const int m = ot * 16 + lo;
        half8 hv;
#pragma unroll
        for (int j = 0; j < 8; ++j) hv[j] = (_Float16)0.0f;
        if (m < 81) {
            const int o = g * 81 + m;
            const int c = c0 * 32 + q * 8;
            const float sc = (c >= 128) ? 2.0f : 1.0f;
            const float* wr = wof + (size_t)o * 256 + c;
#pragma unroll
            for (int j = 0; j < 8; ++j) hv[j] = (_Float16)(wr[j] * sc);
        }
        woxg[i] = hv;
    } else {
        const int i = (bid - 608) * 256 + tid;     // < 57344
        const int q = i & 3, lo = (i >> 2) & 15, ot = (i >> 6) & 7;
        const int gp = i >> 9;
        const int pair = gp % 14, g = gp / 14;
        const int tap = pair * 2 + (q >> 1);
        half8 hv;
#pragma unroll
        for (int j = 0; j < 8; ++j) hv[j] = (_Float16)0.0f;
        if (tap < K3) {
            const int o = ot * 16 + lo;
            const int cb = g * 16 + (q & 1) * 8;
            const float* wr = wdcn + ((size_t)(o * CSN + cb)) * K3 + tap;
#pragma unroll
            for (int j = 0; j < 8; ++j) hv[j] = (_Float16)wr[(size_t)j * K3];
        }
        wtx2[i] = hv;
    }
}

// ---------------------------------------------------------------------------
// Kernel 2: MEGA — R20 = R19 + staging via global_load_lds with
// PRE-SWIZZLED SOURCE (m173 pattern):
//  * LDS dest is linear in c (slot c at regB + c*16, wave-uniform base +
//    lane*16); the parity swizzle moves to the global source: lane c
//    fetches half hf = (c&1) ^ parity(v), so the LDS image is
//    byte-identical to R19's (gather code untouched).
//  * Deletes ~225 ds_write_b128 + VGPR roundtrip per block-g (~9% of the
//    LDS-pipe cycle budget); loads drain under phase-A MFMA (T14 for free,
//    zero register lifetime across phases — not the R18 spill pattern).
//  * regB padded 1800 -> 1856 slots so the partial wave at it=3 stays
//    in-bounds. LDS 79872 B x 2 blocks <= 160K.
// LDS: catx 32K | regB 29696 | offls(11.0K) aliased w/ sampx dbuf (17K).
// ---------------------------------------------------------------------------
#define REGB_OFF 32768
#define SH2_OFF  62464          // 32768 + 1856*16
#define LDS_TOTAL 79872
#define SROW 68                 // padded sampx row stride (half8)
#define OSTR 68                 // offls row stride (f16)

__global__ __launch_bounds__(512, 4) void mega_kernel(
    const float* __restrict__ dst, const float4* __restrict__ up4,
    const half8* __restrict__ woxg, const half8* __restrict__ wtx2,
    float* __restrict__ out)
{
    __shared__ __align__(16) char ldsraw[LDS_TOTAL];
    half8* catx = (half8*)ldsraw;
    char* regB = ldsraw + REGB_OFF;
    _Float16* offls = (_Float16*)(ldsraw + SH2_OFF);
    half8* sampx = (half8*)(ldsraw + SH2_OFF);   // dbuf: +0 / +544 half8

    const int tid = threadIdx.x;
    const int b = blockIdx.y;
    const int cb = blockIdx.x;
    const int X4 = (cb & 7) << 2, Y4 = ((cb >> 3) & 7) << 2, Z4 = (cb >> 6) << 2;

    // ---- phase 0: stage catx with cube columns ----
    {
        const int co = tid >> 4, pq = tid & 15;
        const int cz = pq >> 2, cy = pq & 3;
        const int pbase = ((Z4 + cz) << 10) + ((Y4 + cy) << 5) + X4;
        if (co < 16) {                      // dst channels, fp32 -> f16
            const int c = co * 8;
            const float* dp = dst + ((size_t)(b * CDN + c) << 14) + pbase;
            float vv[32];
#pragma unroll
            for (int j = 0; j < 8; ++j)
                *(float4*)&vv[j * 4] = *(const float4*)(dp + ((size_t)j << 14));
#pragma unroll
            for (int i = 0; i < 4; ++i) {
                half8 hh;
#pragma unroll
                for (int j = 0; j < 8; ++j) hh[j] = (_Float16)vv[j * 4 + i];
                catx[co * 64 + pq * 4 + i] = hh;
            }
        } else {                            // upsampled halves: f16 copy
            const int g2 = (co - 16) >> 1, oct = (co - 16) & 1;
            const half8* u8 = (const half8*)up4;
            const size_t base =
                ((size_t)((b * GG + g2) * 2 + oct) << 14) + pbase;
#pragma unroll
            for (int i = 0; i < 4; ++i)
                catx[co * 64 + pq * 4 + i] = u8[base + i];
        }
    }

    const int w = tid >> 6, l = tid & 63, lo = l & 15, q = l >> 4;
    const int t2 = w >> 1, h = w & 1;       // sampling: tap-in-round, ch-half
    const int tp = l;                       // cube column
    const int cz = tp >> 4, cy = (tp >> 2) & 3, cx = tp & 3;
    const int zoA = Z4 + cz, yoA = Y4 + cy, xoA = X4 + cx;

    f32x4 acc[4];
#pragma unroll
    for (int ps = 0; ps < 4; ++ps) acc[ps] = (f32x4){0.f, 0.f, 0.f, 0.f};

#pragma unroll 1
    for (int g = 0; g < 8; ++g) {
        __syncthreads();    // prior rounds done reading regB / sampx(offls)

        // ---- region staging: global_load_lds, linear dest, swizzled src ----
#pragma unroll
        for (int it = 0; it < 4; ++it) {
            const int c = tid + it * 512;
            if (c < 1800) {
                const int v = c >> 1;
                const int zz = v / 100, r2 = v - zz * 100;
                const int yy = r2 / 10, xx = r2 - yy * 10;
                const int vz = min(max(Z4 - 3 + zz, 0), DD - 1);
                const int vy = min(max(Y4 - 3 + yy, 0), DH - 1);
                const int vx = min(max(X4 - 3 + xx, 0), DW - 1);
                const int par = (xx + yy + zz) & 1;
                const int hf = (c & 1) ^ par;            // swizzle via source
                const float4* gsrc =
                    up4 + (size_t)((b * GG + g) * 2 + hf) * PP +
                    (vz << 10) + (vy << 5) + vx;
                sf4* ldst = (sf4*)(regB + ((it << 9) + (w << 6)) * 16);
                __builtin_amdgcn_global_load_lds((gf4*)gsrc, ldst, 16, 0, 0);
            }
        }

        // ---- phase A: offset mini-GEMM, A reused across all 4 ps ----
        if (w < 6) {
            f32x4 a[4];
#pragma unroll
            for (int ps = 0; ps < 4; ++ps) a[ps] = (f32x4){0.f, 0.f, 0.f, 0.f};
            __builtin_amdgcn_s_setprio(1);
#pragma unroll
            for (int c0 = 0; c0 < 8; ++c0) {
                const half8 A =
                    woxg[(size_t)((((g * 8 + c0) * 6 + w) * 16 + lo) * 4 + q)];
#pragma unroll
                for (int ps = 0; ps < 4; ++ps) {
                    const half8 B = catx[(c0 * 4 + q) * 64 + ps * 16 + lo];
                    a[ps] = __builtin_amdgcn_mfma_f32_16x16x32_f16(A, B, a[ps], 0, 0, 0);
                }
            }
            __builtin_amdgcn_s_setprio(0);
#pragma unroll
            for (int ps = 0; ps < 4; ++ps) {
#pragma unroll
                for (int r = 0; r < 4; ++r) {
                    const int m = w * 16 + q * 4 + r;
                    if (m < 81)
                        offls[m * OSTR + ps * 16 + lo] = (_Float16)a[ps][r];
                }
            }
        }
        __syncthreads();

        // ---- offsets -> registers (frees offls space for sampx) ----
        float offv[7][3];
#pragma unroll
        for (int r = 0; r < 7; ++r) {
            const int tap = r * 4 + t2;
            if (tap < K3) {
#pragma unroll
                for (int c = 0; c < 3; ++c)
                    offv[r][c] = (float)offls[(tap * 3 + c) * OSTR + tp];
            }
        }
        __syncthreads();

        // ---- 7 rounds x (sample 4 taps -> A-prefetch -> barrier -> MFMA) ----
#pragma unroll
        for (int r = 0; r < 7; ++r) {
            half8* dbuf = sampx + (r & 1) * 544;
            const int tap = r * 4 + t2;
            if (tap < K3) {
                const int kz = tap / 9 - 1;
                const int ky = (tap / 3) % 3 - 1;
                const int kx = (tap % 3) - 1;
                const float z = (float)(zoA + kz) + offv[r][0];
                const float y = (float)(yoA + ky) + offv[r][1];
                const float x = (float)(xoA + kx) + offv[r][2];
                const float zf = floorf(z), yf = floorf(y), xf = floorf(x);
                const float fz = z - zf, fy = y - yf, fx = x - xf;
                const int z0i = (int)zf, y0i = (int)yf, x0i = (int)xf;

                const float wz0 = ((unsigned)z0i < DD) ? 1.f - fz : 0.f;
                const float wz1 = ((unsigned)(z0i + 1) < DD) ? fz : 0.f;
                const float wy0 = ((unsigned)y0i < DH) ? 1.f - fy : 0.f;
                const float wy1 = ((unsigned)(y0i + 1) < DH) ? fy : 0.f;
                const float wx0 = ((unsigned)x0i < DW) ? 1.f - fx : 0.f;
                const float wx1 = ((unsigned)(x0i + 1) < DW) ? fx : 0.f;
                float wcs[8];
                wcs[0] = wz0 * wy0 * wx0; wcs[1] = wz0 * wy0 * wx1;
                wcs[2] = wz0 * wy1 * wx0; wcs[3] = wz0 * wy1 * wx1;
                wcs[4] = wz1 * wy0 * wx0; wcs[5] = wz1 * wy0 * wx1;
                wcs[6] = wz1 * wy1 * wx0; wcs[7] = wz1 * wy1 * wx1;

                const int sz0 = z0i - (Z4 - 3);
                const int sy0 = y0i - (Y4 - 3);
                const int sx0 = x0i - (X4 - 3);

                __align__(16) __half2 acch[4];
#pragma unroll
                for (int rr = 0; rr < 4; ++rr) acch[rr] = __floats2half2_rn(0.f, 0.f);

                if ((unsigned)sz0 <= 7u && (unsigned)sy0 <= 8u &&
                    (unsigned)sx0 <= 8u) {
                    // LDS region gather, parity-swizzled half placement
                    const int v000 = (sz0 * 10 + sy0) * 10 + sx0;
                    const int s0 = (sx0 + sy0 + sz0 + h) & 1;   // base parity
                    const int s1 = s0 ^ 1;
                    const int vox[8] = {v000,       v000 + 1,
                                        v000 + 10,  v000 + 11,
                                        v000 + 100, v000 + 101,
                                        v000 + 110, v000 + 111};
                    const int sws[8] = {s0, s1, s1, s0, s1, s0, s0, s1};
                    half8 hv[8];
#pragma unroll
                    for (int ci = 0; ci < 8; ++ci)
                        hv[ci] = *(const half8*)(regB + vox[ci] * 32 + sws[ci] * 16);
#pragma unroll
                    for (int ci = 0; ci < 8; ++ci) {
                        const __half2 wh = __float2half2_rn(wcs[ci]);
                        const __half2* h2 = (const __half2*)&hv[ci];
#pragma unroll
                        for (int rr = 0; rr < 4; ++rr)
                            acch[rr] = __hfma2(h2[rr], wh, acch[rr]);
                    }
                } else {
                    // exact global fallback (rare)
                    const int iz0 = min(max(z0i, 0), DD - 1);
                    const int iz1 = min(max(z0i + 1, 0), DD - 1);
                    const int iy0 = min(max(y0i, 0), DH - 1);
                    const int iy1 = min(max(y0i + 1, 0), DH - 1);
                    const int ix0 = min(max(x0i, 0), DW - 1);
                    const int ix1 = min(max(x0i + 1, 0), DW - 1);
                    const int v000 = (iz0 << 10) + (iy0 << 5) + ix0;
                    const int dzo = (iz1 - iz0) << 10;
                    const int dyo = (iy1 - iy0) << 5;
                    const int dxo = ix1 - ix0;
                    const int vox[8] = {v000,             v000 + dxo,
                                        v000 + dyo,       v000 + dyo + dxo,
                                        v000 + dzo,       v000 + dzo + dxo,
                                        v000 + dzo + dyo, v000 + dzo + dyo + dxo};
                    const float4* baseF =
                        up4 + (size_t)((b * GG + g) * 2 + h) * PP;
#pragma unroll
                    for (int ci = 0; ci < 8; ++ci) {
                        const float4 u = baseF[vox[ci]];
                        const __half2 wh = __float2half2_rn(wcs[ci]);
                        const __half2* h2 = (const __half2*)&u;
#pragma unroll
                        for (int rr = 0; rr < 4; ++rr)
                            acch[rr] = __hfma2(h2[rr], wh, acch[rr]);
                    }
                }
                dbuf[(t2 * 2 + h) * SROW + tp + (tp >> 4)] = *(half8*)&acch[0];
            }

            // ---- A-prefetch for this round's MFMA: latency drains in barrier
            half8 Apre[2];
#pragma unroll
            for (int p = 0; p < 2; ++p)
                Apre[p] = wtx2[(size_t)(
                    (((g * 14 + r * 2 + p) * 8 + w) * 16 + lo) * 4 + q)];
            __syncthreads();

            // ---- MFMA: wave w = o-tile w; 2 pairs x 4 p-subtiles ----
            __builtin_amdgcn_s_setprio(1);
#pragma unroll
            for (int p = 0; p < 2; ++p) {
#pragma unroll
                for (int ps = 0; ps < 4; ++ps) {
                    const half8 B = dbuf[(p * 4 + q) * SROW + ps * 17 + lo];
                    acc[ps] = __builtin_amdgcn_mfma_f32_16x16x32_f16(Apre[p], B, acc[ps], 0, 0, 0);
                }
            }
            __builtin_amdgcn_s_setprio(0);
        }
    }

    // ---- epilogue: ReLU + store (cube addressing) ----
#pragma unroll
    for (int ps = 0; ps < 4; ++ps) {
        const int zo = Z4 + ps, yo = Y4 + ((lo >> 2) & 3), xo = X4 + (lo & 3);
        const int paddr = (zo << 10) + (yo << 5) + xo;
#pragma unroll
        for (int r = 0; r < 4; ++r) {
            const int o = w * 16 + q * 4 + r;
            out[((size_t)(b * CDN + o) << 14) + paddr] = fmaxf(acc[ps][r], 0.f);
        }
    }
}

// ---------------------------------------------------------------------------
extern "C" void kernel_launch(void* const* d_in, const int* in_sizes, int n_in,
                              void* d_out, int out_size, void* d_ws, size_t ws_size,
                              hipStream_t stream)
{
    const float* src1x = (const float*)d_in[0];   // [2,128,8,16,16]
    const float* dst2x = (const float*)d_in[1];   // [2,128,16,32,32]
    const float* w_off = (const float*)d_in[2];   // [648,256]
    const float* w_dcn = (const float*)d_in[3];   // [128,128,3,3,3]
    float* out = (float*)d_out;

    char* ws = (char*)d_ws;
    half8* uph8 = (half8*)(ws);                    // 8,388,608 B
    half8* woxg = (half8*)(ws + 8388608);          //   393,216 B
    half8* wtx2 = (half8*)(ws + 8781824);          //   917,504 B

    prep_kernel<<<dim3(832), dim3(256), 0, stream>>>(
        src1x, w_off, w_dcn, uph8, woxg, wtx2);
    mega_kernel<<<dim3(256, BB), dim3(512), 0, stream>>>(
        dst2x, (const float4*)uph8, woxg, wtx2, out);
}

// Round 9
// 195.573 us; speedup vs baseline: 1.2218x; 1.2218x over previous
//
#include <hip/hip_runtime.h>
#include <hip/hip_fp16.h>
#include <math.h>

// Problem constants
#define BB   2
#define CSN  128
#define CDN  128
#define SD   8
#define SH   16
#define SW   16
#define DD   16
#define DH   32
#define DW   32
#define PP   (DD*DH*DW)   // 16384
#define GG   8
#define K3   27
#define OO   648

typedef _Float16 half8 __attribute__((ext_vector_type(8)));
typedef float f32x4 __attribute__((ext_vector_type(4)));

// ---------------------------------------------------------------------------
// Kernel 1: PREP — upsample + weight packs (R16 version, unrolled out-loop).
// ---------------------------------------------------------------------------
__global__ __launch_bounds__(256) void prep_kernel(
    const float* __restrict__ src, const float* __restrict__ wof,
    const float* __restrict__ wdcn, half8* __restrict__ uph8,
    half8* __restrict__ woxg, half8* __restrict__ wtx2)
{
    __shared__ float slab[2 * 8 * 16 * 17];
    const int bid = blockIdx.x;
    const int tid = threadIdx.x;

    if (bid < 512) {
        const int zo = bid & 15, pl = bid >> 4;
        const int h = pl & 1, g = (pl >> 1) & 7, b = pl >> 4;
        const int z0 = (zo - 1) >> 1;
        const float fz = (zo & 1) ? 0.25f : 0.75f;
        {
            const int zi = tid >> 7, cc = (tid >> 4) & 7, y = tid & 15;
            const int zsrc = min(max(z0 + zi, 0), SD - 1);
            const float* srow = src +
                (((size_t)(b * CSN + g * 16 + h * 8 + cc) * SD + zsrc) * SH + y) * SW;
            float* drow = &slab[((zi * 8 + cc) * 16 + y) * 17];
            *(float4*)(drow)      = *(const float4*)(srow);
            *(float4*)(drow + 4)  = *(const float4*)(srow + 4);
            *(float4*)(drow + 8)  = *(const float4*)(srow + 8);
            *(float4*)(drow + 12) = *(const float4*)(srow + 12);
        }
        __syncthreads();

        const float wz0 = 1.f - fz, wz1 = fz;
#pragma unroll
        for (int i = 0; i < 4; ++i) {
            const int pp = tid + i * 256;
            const int yo = pp >> 5, xo = pp & 31;
            const int y0 = (yo - 1) >> 1;
            const float fy = (yo & 1) ? 0.25f : 0.75f;
            const int ys0 = max(y0, 0), ys1 = min(y0 + 1, SH - 1);
            const int x0 = (xo - 1) >> 1;
            const float fx = (xo & 1) ? 0.25f : 0.75f;
            const int xs0 = max(x0, 0), xs1 = min(x0 + 1, SW - 1);
            const float w00 = (1.f - fy) * (1.f - fx), w01 = (1.f - fy) * fx;
            const float w10 = fy * (1.f - fx),         w11 = fy * fx;
            const int a00 = ys0 * 17 + xs0, a01 = ys0 * 17 + xs1;
            const int a10 = ys1 * 17 + xs0, a11 = ys1 * 17 + xs1;

            half8 hv;
#pragma unroll
            for (int cc = 0; cc < 8; ++cc) {
                const float* pa = &slab[(cc * 16) * 17];
                const float* pb = &slab[((8 + cc) * 16) * 17];
                const float s0 = w00 * pa[a00] + w01 * pa[a01]
                               + w10 * pa[a10] + w11 * pa[a11];
                const float s1 = w00 * pb[a00] + w01 * pb[a01]
                               + w10 * pb[a10] + w11 * pb[a11];
                hv[cc] = (_Float16)(wz0 * s0 + wz1 * s1);
            }
            uph8[(size_t)pl * PP + zo * 1024 + pp] = hv;
        }
    } else if (bid < 608) {
        const int i = (bid - 512) * 256 + tid;     // < 24576
        const int q = i & 3, lo = (i >> 2) & 15;
        const int t6 = i >> 6;
        const int ot = t6 % 6;
        const int gc0 = t6 / 6;
        const int c0 = gc0 & 7, g = gc0 >> 3;
        const int m = ot * 16 + lo;
        half8 hv;
#pragma unroll
        for (int j = 0; j < 8; ++j) hv[j] = (_Float16)0.0f;
        if (m < 81) {
            const int o = g * 81 + m;
            const int c = c0 * 32 + q * 8;
            const float sc = (c >= 128) ? 2.0f : 1.0f;
            const float* wr = wof + (size_t)o * 256 + c;
#pragma unroll
            for (int j = 0; j < 8; ++j) hv[j] = (_Float16)(wr[j] * sc);
        }
        woxg[i] = hv;
    } else {
        const int i = (bid - 608) * 256 + tid;     // < 57344
        const int q = i & 3, lo = (i >> 2) & 15, ot = (i >> 6) & 7;
        const int gp = i >> 9;
        const int pair = gp % 14, g = gp / 14;
        const int tap = pair * 2 + (q >> 1);
        half8 hv;
#pragma unroll
        for (int j = 0; j < 8; ++j) hv[j] = (_Float16)0.0f;
        if (tap < K3) {
            const int o = ot * 16 + lo;
            const int cb = g * 16 + (q & 1) * 8;
            const float* wr = wdcn + ((size_t)(o * CSN + cb)) * K3 + tap;
#pragma unroll
            for (int j = 0; j < 8; ++j) hv[j] = (_Float16)wr[(size_t)j * K3];
        }
        wtx2[i] = hv;
    }
}

// ---------------------------------------------------------------------------
// Kernel 2: MEGA — R21 = R19 (best: 137.1 us; VGPR-roundtrip staging
// restored after R20's global_load_lds cache blowout) + barrier reduction:
//  * offls moved from dbuf0-alias to dbuf1-alias + 2.3KB extension
//    (offls = sampx + 544 h8). Disjointness from dbuf0 makes two of the
//    ten per-g barriers vacuous:
//      - top-of-g barrier: regB covered by r=6 post-sample barrier; dbuf1's
//        last reader (r=5 MFMA) precedes it in program order.
//      - post-offv barrier: offv is register-resident before any wave
//        passes the r=0 barrier; r=1's dbuf1 write is ordered behind it.
//    80 -> 65 barriers/block; staging/phase-A of g+1 overlaps r=6 MFMA.
//  * one barrier added after phase-0 catx staging (was covered by the
//    deleted g=0 top barrier).
// LDS: catx 32K | regB 28.8K | dbuf0 8.5K | dbuf1(8.5K)+ext = offls 11K
//   => 81296 B, 2 blocks/CU (162592 <= 163840).
// ---------------------------------------------------------------------------
#define REGB_OFF 32768
#define SH2_OFF  61568
#define OFFLS_OFF 70272         // SH2_OFF + 544*16 (dbuf1 base)
#define LDS_TOTAL 81296
#define SROW 68                 // padded sampx row stride (half8)
#define OSTR 68                 // offls row stride (f16)

__global__ __launch_bounds__(512, 4) void mega_kernel(
    const float* __restrict__ dst, const float4* __restrict__ up4,
    const half8* __restrict__ woxg, const half8* __restrict__ wtx2,
    float* __restrict__ out)
{
    __shared__ __align__(16) char ldsraw[LDS_TOTAL];
    half8* catx = (half8*)ldsraw;
    char* regB = ldsraw + REGB_OFF;
    _Float16* offls = (_Float16*)(ldsraw + OFFLS_OFF);
    half8* sampx = (half8*)(ldsraw + SH2_OFF);   // dbuf: +0 / +544 half8

    const int tid = threadIdx.x;
    const int b = blockIdx.y;
    const int cb = blockIdx.x;
    const int X4 = (cb & 7) << 2, Y4 = ((cb >> 3) & 7) << 2, Z4 = (cb >> 6) << 2;

    // ---- phase 0: stage catx with cube columns ----
    {
        const int co = tid >> 4, pq = tid & 15;
        const int cz = pq >> 2, cy = pq & 3;
        const int pbase = ((Z4 + cz) << 10) + ((Y4 + cy) << 5) + X4;
        if (co < 16) {                      // dst channels, fp32 -> f16
            const int c = co * 8;
            const float* dp = dst + ((size_t)(b * CDN + c) << 14) + pbase;
            float vv[32];
#pragma unroll
            for (int j = 0; j < 8; ++j)
                *(float4*)&vv[j * 4] = *(const float4*)(dp + ((size_t)j << 14));
#pragma unroll
            for (int i = 0; i < 4; ++i) {
                half8 hh;
#pragma unroll
                for (int j = 0; j < 8; ++j) hh[j] = (_Float16)vv[j * 4 + i];
                catx[co * 64 + pq * 4 + i] = hh;
            }
        } else {                            // upsampled halves: f16 copy
            const int g2 = (co - 16) >> 1, oct = (co - 16) & 1;
            const half8* u8 = (const half8*)up4;
            const size_t base =
                ((size_t)((b * GG + g2) * 2 + oct) << 14) + pbase;
#pragma unroll
            for (int i = 0; i < 4; ++i)
                catx[co * 64 + pq * 4 + i] = u8[base + i];
        }
    }
    __syncthreads();    // catx ready for all g (replaces g=0 top barrier)

    const int w = tid >> 6, l = tid & 63, lo = l & 15, q = l >> 4;
    const int t2 = w >> 1, h = w & 1;       // sampling: tap-in-round, ch-half
    const int tp = l;                       // cube column
    const int cz = tp >> 4, cy = (tp >> 2) & 3, cx = tp & 3;
    const int zoA = Z4 + cz, yoA = Y4 + cy, xoA = X4 + cx;

    f32x4 acc[4];
#pragma unroll
    for (int ps = 0; ps < 4; ++ps) acc[ps] = (f32x4){0.f, 0.f, 0.f, 0.f};

#pragma unroll 1
    for (int g = 0; g < 8; ++g) {
        // (no top-of-g barrier: regB free after r=6 post-sample barrier;
        //  dbuf1/offls free after r=5 MFMA which precedes it in prog order)

        // ---- region staging: interleaved (hf = c&1), parity-swizzled ----
#pragma unroll 1
        for (int c = tid; c < 1800; c += 512) {
            const int hf = c & 1;
            const int v = c >> 1;
            const int zz = v / 100, r2 = v - zz * 100;
            const int yy = r2 / 10, xx = r2 - yy * 10;
            const int vz = min(max(Z4 - 3 + zz, 0), DD - 1);
            const int vy = min(max(Y4 - 3 + yy, 0), DH - 1);
            const int vx = min(max(X4 - 3 + xx, 0), DW - 1);
            const float4 val =
                up4[(size_t)((b * GG + g) * 2 + hf) * PP +
                    (vz << 10) + (vy << 5) + vx];
            const int sw = (xx + yy + zz + hf) & 1;      // parity swizzle
            *(float4*)(regB + v * 32 + sw * 16) = val;
        }

        // ---- phase A: offset mini-GEMM, A reused across all 4 ps ----
        if (w < 6) {
            f32x4 a[4];
#pragma unroll
            for (int ps = 0; ps < 4; ++ps) a[ps] = (f32x4){0.f, 0.f, 0.f, 0.f};
            __builtin_amdgcn_s_setprio(1);
#pragma unroll
            for (int c0 = 0; c0 < 8; ++c0) {
                const half8 A =
                    woxg[(size_t)((((g * 8 + c0) * 6 + w) * 16 + lo) * 4 + q)];
#pragma unroll
                for (int ps = 0; ps < 4; ++ps) {
                    const half8 B = catx[(c0 * 4 + q) * 64 + ps * 16 + lo];
                    a[ps] = __builtin_amdgcn_mfma_f32_16x16x32_f16(A, B, a[ps], 0, 0, 0);
                }
            }
            __builtin_amdgcn_s_setprio(0);
#pragma unroll
            for (int ps = 0; ps < 4; ++ps) {
#pragma unroll
                for (int r = 0; r < 4; ++r) {
                    const int m = w * 16 + q * 4 + r;
                    if (m < 81)
                        offls[m * OSTR + ps * 16 + lo] = (_Float16)a[ps][r];
                }
            }
        }
        __syncthreads();    // staging + offls complete

        // ---- offsets -> registers (reads ordered vs r=1 write by r=0 bar) ----
        float offv[7][3];
#pragma unroll
        for (int r = 0; r < 7; ++r) {
            const int tap = r * 4 + t2;
            if (tap < K3) {
#pragma unroll
                for (int c = 0; c < 3; ++c)
                    offv[r][c] = (float)offls[(tap * 3 + c) * OSTR + tp];
            }
        }
        // (no post-offv barrier: r=0 writes dbuf0, disjoint from offls)

        // ---- 7 rounds x (sample 4 taps -> A-prefetch -> barrier -> MFMA) ----
#pragma unroll
        for (int r = 0; r < 7; ++r) {
            half8* dbuf = sampx + (r & 1) * 544;
            const int tap = r * 4 + t2;
            if (tap < K3) {
                const int kz = tap / 9 - 1;
                const int ky = (tap / 3) % 3 - 1;
                const int kx = (tap % 3) - 1;
                const float z = (float)(zoA + kz) + offv[r][0];
                const float y = (float)(yoA + ky) + offv[r][1];
                const float x = (float)(xoA + kx) + offv[r][2];
                const float zf = floorf(z), yf = floorf(y), xf = floorf(x);
                const float fz = z - zf, fy = y - yf, fx = x - xf;
                const int z0i = (int)zf, y0i = (int)yf, x0i = (int)xf;

                const float wz0 = ((unsigned)z0i < DD) ? 1.f - fz : 0.f;
                const float wz1 = ((unsigned)(z0i + 1) < DD) ? fz : 0.f;
                const float wy0 = ((unsigned)y0i < DH) ? 1.f - fy : 0.f;
                const float wy1 = ((unsigned)(y0i + 1) < DH) ? fy : 0.f;
                const float wx0 = ((unsigned)x0i < DW) ? 1.f - fx : 0.f;
                const float wx1 = ((unsigned)(x0i + 1) < DW) ? fx : 0.f;
                float wcs[8];
                wcs[0] = wz0 * wy0 * wx0; wcs[1] = wz0 * wy0 * wx1;
                wcs[2] = wz0 * wy1 * wx0; wcs[3] = wz0 * wy1 * wx1;
                wcs[4] = wz1 * wy0 * wx0; wcs[5] = wz1 * wy0 * wx1;
                wcs[6] = wz1 * wy1 * wx0; wcs[7] = wz1 * wy1 * wx1;

                const int sz0 = z0i - (Z4 - 3);
                const int sy0 = y0i - (Y4 - 3);
                const int sx0 = x0i - (X4 - 3);

                __align__(16) __half2 acch[4];
#pragma unroll
                for (int rr = 0; rr < 4; ++rr) acch[rr] = __floats2half2_rn(0.f, 0.f);

                if ((unsigned)sz0 <= 7u && (unsigned)sy0 <= 8u &&
                    (unsigned)sx0 <= 8u) {
                    // LDS region gather, parity-swizzled half placement
                    const int v000 = (sz0 * 10 + sy0) * 10 + sx0;
                    const int s0 = (sx0 + sy0 + sz0 + h) & 1;   // base parity
                    const int s1 = s0 ^ 1;
                    const int vox[8] = {v000,       v000 + 1,
                                        v000 + 10,  v000 + 11,
                                        v000 + 100, v000 + 101,
                                        v000 + 110, v000 + 111};
                    const int sws[8] = {s0, s1, s1, s0, s1, s0, s0, s1};
                    half8 hv[8];
#pragma unroll
                    for (int ci = 0; ci < 8; ++ci)
                        hv[ci] = *(const half8*)(regB + vox[ci] * 32 + sws[ci] * 16);
#pragma unroll
                    for (int ci = 0; ci < 8; ++ci) {
                        const __half2 wh = __float2half2_rn(wcs[ci]);
                        const __half2* h2 = (const __half2*)&hv[ci];
#pragma unroll
                        for (int rr = 0; rr < 4; ++rr)
                            acch[rr] = __hfma2(h2[rr], wh, acch[rr]);
                    }
                } else {
                    // exact global fallback (rare)
                    const int iz0 = min(max(z0i, 0), DD - 1);
                    const int iz1 = min(max(z0i + 1, 0), DD - 1);
                    const int iy0 = min(max(y0i, 0), DH - 1);
                    const int iy1 = min(max(y0i + 1, 0), DH - 1);
                    const int ix0 = min(max(x0i, 0), DW - 1);
                    const int ix1 = min(max(x0i + 1, 0), DW - 1);
                    const int v000 = (iz0 << 10) + (iy0 << 5) + ix0;
                    const int dzo = (iz1 - iz0) << 10;
                    const int dyo = (iy1 - iy0) << 5;
                    const int dxo = ix1 - ix0;
                    const int vox[8] = {v000,             v000 + dxo,
                                        v000 + dyo,       v000 + dyo + dxo,
                                        v000 + dzo,       v000 + dzo + dxo,
                                        v000 + dzo + dyo, v000 + dzo + dyo + dxo};
                    const float4* baseF =
                        up4 + (size_t)((b * GG + g) * 2 + h) * PP;
#pragma unroll
                    for (int ci = 0; ci < 8; ++ci) {
                        const float4 u = baseF[vox[ci]];
                        const __half2 wh = __float2half2_rn(wcs[ci]);
                        const __half2* h2 = (const __half2*)&u;
#pragma unroll
                        for (int rr = 0; rr < 4; ++rr)
                            acch[rr] = __hfma2(h2[rr], wh, acch[rr]);
                    }
                }
                dbuf[(t2 * 2 + h) * SROW + tp + (tp >> 4)] = *(half8*)&acch[0];
            }

            // ---- A-prefetch for this round's MFMA: latency drains in barrier
            half8 Apre[2];
#pragma unroll
            for (int p = 0; p < 2; ++p)
                Apre[p] = wtx2[(size_t)(
                    (((g * 14 + r * 2 + p) * 8 + w) * 16 + lo) * 4 + q)];
            __syncthreads();

            // ---- MFMA: wave w = o-tile w; 2 pairs x 4 p-subtiles ----
            __builtin_amdgcn_s_setprio(1);
#pragma unroll
            for (int p = 0; p < 2; ++p) {
#pragma unroll
                for (int ps = 0; ps < 4; ++ps) {
                    const half8 B = dbuf[(p * 4 + q) * SROW + ps * 17 + lo];
                    acc[ps] = __builtin_amdgcn_mfma_f32_16x16x32_f16(Apre[p], B, acc[ps], 0, 0, 0);
                }
            }
            __builtin_amdgcn_s_setprio(0);
        }
    }

    // ---- epilogue: ReLU + store (cube addressing) ----
#pragma unroll
    for (int ps = 0; ps < 4; ++ps) {
        const int zo = Z4 + ps, yo = Y4 + ((lo >> 2) & 3), xo = X4 + (lo & 3);
        const int paddr = (zo << 10) + (yo << 5) + xo;
#pragma unroll
        for (int r = 0; r < 4; ++r) {
            const int o = w * 16 + q * 4 + r;
            out[((size_t)(b * CDN + o) << 14) + paddr] = fmaxf(acc[ps][r], 0.f);
        }
    }
}

// ---------------------------------------------------------------------------
extern "C" void kernel_launch(void* const* d_in, const int* in_sizes, int n_in,
                              void* d_out, int out_size, void* d_ws, size_t ws_size,
                              hipStream_t stream)
{
    const float* src1x = (const float*)d_in[0];   // [2,128,8,16,16]
    const float* dst2x = (const float*)d_in[1];   // [2,128,16,32,32]
    const float* w_off = (const float*)d_in[2];   // [648,256]
    const float* w_dcn = (const float*)d_in[3];   // [128,128,3,3,3]
    float* out = (float*)d_out;

    char* ws = (char*)d_ws;
    half8* uph8 = (half8*)(ws);                    // 8,388,608 B
    half8* woxg = (half8*)(ws + 8388608);          //   393,216 B
    half8* wtx2 = (half8*)(ws + 8781824);          //   917,504 B

    prep_kernel<<<dim3(832), dim3(256), 0, stream>>>(
        src1x, w_off, w_dcn, uph8, woxg, wtx2);
    mega_kernel<<<dim3(256, BB), dim3(512), 0, stream>>>(
        dst2x, (const float4*)uph8, woxg, wtx2, out);
}

// Round 10
// 192.878 us; speedup vs baseline: 1.2389x; 1.0140x over previous
//
#include <hip/hip_runtime.h>
#include <hip/hip_fp16.h>
#include <math.h>

// Problem constants
#define BB   2
#define CSN  128
#define CDN  128
#define SD   8
#define SH   16
#define SW   16
#define DD   16
#define DH   32
#define DW   32
#define PP   (DD*DH*DW)   // 16384
#define GG   8
#define K3   27
#define OO   648

typedef _Float16 half8 __attribute__((ext_vector_type(8)));
typedef float f32x4 __attribute__((ext_vector_type(4)));
typedef float f32x16 __attribute__((ext_vector_type(16)));

// ---------------------------------------------------------------------------
// Kernel 1: PREP — upsample + weight packs. R22: wtx2 repacked for the
// 32x32x16 A-fragment layout (same total size 57344 half8, same wdcn
// gather pattern): element i = ((g*7+r)*4+m)*256 + ob*64 + l holds, for
// lane l (o = ob*32 + (l&31), h = l>>5), channels cb..cb+7 (cb = g*16+h*8)
// of tap r*4+m.  tap 27 (r=6,m=3) packs zeros.
// ---------------------------------------------------------------------------
__global__ __launch_bounds__(256) void prep_kernel(
    const float* __restrict__ src, const float* __restrict__ wof,
    const float* __restrict__ wdcn, half8* __restrict__ uph8,
    half8* __restrict__ woxg, half8* __restrict__ wtx2)
{
    __shared__ float slab[2 * 8 * 16 * 17];
    const int bid = blockIdx.x;
    const int tid = threadIdx.x;

    if (bid < 512) {
        const int zo = bid & 15, pl = bid >> 4;
        const int h = pl & 1, g = (pl >> 1) & 7, b = pl >> 4;
        const int z0 = (zo - 1) >> 1;
        const float fz = (zo & 1) ? 0.25f : 0.75f;
        {
            const int zi = tid >> 7, cc = (tid >> 4) & 7, y = tid & 15;
            const int zsrc = min(max(z0 + zi, 0), SD - 1);
            const float* srow = src +
                (((size_t)(b * CSN + g * 16 + h * 8 + cc) * SD + zsrc) * SH + y) * SW;
            float* drow = &slab[((zi * 8 + cc) * 16 + y) * 17];
            *(float4*)(drow)      = *(const float4*)(srow);
            *(float4*)(drow + 4)  = *(const float4*)(srow + 4);
            *(float4*)(drow + 8)  = *(const float4*)(srow + 8);
            *(float4*)(drow + 12) = *(const float4*)(srow + 12);
        }
        __syncthreads();

        const float wz0 = 1.f - fz, wz1 = fz;
#pragma unroll
        for (int i = 0; i < 4; ++i) {
            const int pp = tid + i * 256;
            const int yo = pp >> 5, xo = pp & 31;
            const int y0 = (yo - 1) >> 1;
            const float fy = (yo & 1) ? 0.25f : 0.75f;
            const int ys0 = max(y0, 0), ys1 = min(y0 + 1, SH - 1);
            const int x0 = (xo - 1) >> 1;
            const float fx = (xo & 1) ? 0.25f : 0.75f;
            const int xs0 = max(x0, 0), xs1 = min(x0 + 1, SW - 1);
            const float w00 = (1.f - fy) * (1.f - fx), w01 = (1.f - fy) * fx;
            const float w10 = fy * (1.f - fx),         w11 = fy * fx;
            const int a00 = ys0 * 17 + xs0, a01 = ys0 * 17 + xs1;
            const int a10 = ys1 * 17 + xs0, a11 = ys1 * 17 + xs1;

            half8 hv;
#pragma unroll
            for (int cc = 0; cc < 8; ++cc) {
                const float* pa = &slab[(cc * 16) * 17];
                const float* pb = &slab[((8 + cc) * 16) * 17];
                const float s0 = w00 * pa[a00] + w01 * pa[a01]
                               + w10 * pa[a10] + w11 * pa[a11];
                const float s1 = w00 * pb[a00] + w01 * pb[a01]
                               + w10 * pb[a10] + w11 * pb[a11];
                hv[cc] = (_Float16)(wz0 * s0 + wz1 * s1);
            }
            uph8[(size_t)pl * PP + zo * 1024 + pp] = hv;
        }
    } else if (bid < 608) {
        const int i = (bid - 512) * 256 + tid;     // < 24576
        const int q = i & 3, lo = (i >> 2) & 15;
        const int t6 = i >> 6;
        const int ot = t6 % 6;
        const int gc0 = t6 / 6;
        const int c0 = gc0 & 7, g = gc0 >> 3;
        const int m = ot * 16 + lo;
        half8 hv;
#pragma unroll
        for (int j = 0; j < 8; ++j) hv[j] = (_Float16)0.0f;
        if (m < 81) {
            const int o = g * 81 + m;
            const int c = c0 * 32 + q * 8;
            const float sc = (c >= 128) ? 2.0f : 1.0f;
            const float* wr = wof + (size_t)o * 256 + c;
#pragma unroll
            for (int j = 0; j < 8; ++j) hv[j] = (_Float16)(wr[j] * sc);
        }
        woxg[i] = hv;
    } else {
        const int i = (bid - 608) * 256 + tid;     // < 57344
        const int l = i & 63;
        const int ob = (i >> 6) & 3;
        const int m = (i >> 8) & 3;
        const int gr = i >> 10;                    // g*7 + r, < 56
        const int r = gr % 7, g = gr / 7;
        const int tap = r * 4 + m;
        half8 hv;
#pragma unroll
        for (int j = 0; j < 8; ++j) hv[j] = (_Float16)0.0f;
        if (tap < K3) {
            const int o = ob * 32 + (l & 31);
            const int cb = g * 16 + (l >> 5) * 8;
            const float* wr = wdcn + ((size_t)(o * CSN + cb)) * K3 + tap;
#pragma unroll
            for (int j = 0; j < 8; ++j) hv[j] = (_Float16)wr[(size_t)j * K3];
        }
        wtx2[i] = hv;
    }
}

// ---------------------------------------------------------------------------
// Kernel 2: MEGA — R22 = R21 (best: 136.0 us; barrier-reduced schedule,
// VGPR-roundtrip staging, offls on dbuf1) with the DCN GEMM switched from
// 16x16x32 to 32x32x16:
//  * wave output tile 32o x 32p (8 waves = 4 ob x 2 pt) -> 4 MFMA + 4
//    ds_read_b128 B-fragments per round instead of 8+8.  Saves ~3584
//    b128 reads/CU (~43k LDS-pipe cycles, 13% of budget) on the
//    dominant pipe.  Sampling, dbuf layout, staging, gather, phase A,
//    and the R21 barrier schedule are byte-identical.
//  * B fragment: lane l reads dbuf[row = m*2 + (l>>5)][col = pt*32+(l&31)]
//    (same rows/cols as before, fewer reads).  A from repacked wtx2.
//  * C/D layout (guide §3, m74/m101): col = lane&31,
//    row = (reg&3) + 8*(reg>>2) + 4*(lane>>5).
// LDS: catx 32K | regB 28.8K | dbuf0 8.5K | dbuf1+ext = offls 11K
//   => 81296 B, 2 blocks/CU.
// ---------------------------------------------------------------------------
#define REGB_OFF 32768
#define SH2_OFF  61568
#define OFFLS_OFF 70272         // SH2_OFF + 544*16 (dbuf1 base)
#define LDS_TOTAL 81296
#define SROW 68                 // padded sampx row stride (half8)
#define OSTR 68                 // offls row stride (f16)

__global__ __launch_bounds__(512, 4) void mega_kernel(
    const float* __restrict__ dst, const float4* __restrict__ up4,
    const half8* __restrict__ woxg, const half8* __restrict__ wtx2,
    float* __restrict__ out)
{
    __shared__ __align__(16) char ldsraw[LDS_TOTAL];
    half8* catx = (half8*)ldsraw;
    char* regB = ldsraw + REGB_OFF;
    _Float16* offls = (_Float16*)(ldsraw + OFFLS_OFF);
    half8* sampx = (half8*)(ldsraw + SH2_OFF);   // dbuf: +0 / +544 half8

    const int tid = threadIdx.x;
    const int b = blockIdx.y;
    const int cb = blockIdx.x;
    const int X4 = (cb & 7) << 2, Y4 = ((cb >> 3) & 7) << 2, Z4 = (cb >> 6) << 2;

    // ---- phase 0: stage catx with cube columns ----
    {
        const int co = tid >> 4, pq = tid & 15;
        const int cz = pq >> 2, cy = pq & 3;
        const int pbase = ((Z4 + cz) << 10) + ((Y4 + cy) << 5) + X4;
        if (co < 16) {                      // dst channels, fp32 -> f16
            const int c = co * 8;
            const float* dp = dst + ((size_t)(b * CDN + c) << 14) + pbase;
            float vv[32];
#pragma unroll
            for (int j = 0; j < 8; ++j)
                *(float4*)&vv[j * 4] = *(const float4*)(dp + ((size_t)j << 14));
#pragma unroll
            for (int i = 0; i < 4; ++i) {
                half8 hh;
#pragma unroll
                for (int j = 0; j < 8; ++j) hh[j] = (_Float16)vv[j * 4 + i];
                catx[co * 64 + pq * 4 + i] = hh;
            }
        } else {                            // upsampled halves: f16 copy
            const int g2 = (co - 16) >> 1, oct = (co - 16) & 1;
            const half8* u8 = (const half8*)up4;
            const size_t base =
                ((size_t)((b * GG + g2) * 2 + oct) << 14) + pbase;
#pragma unroll
            for (int i = 0; i < 4; ++i)
                catx[co * 64 + pq * 4 + i] = u8[base + i];
        }
    }
    __syncthreads();    // catx ready for all g (replaces g=0 top barrier)

    const int w = tid >> 6, l = tid & 63, lo = l & 15, q = l >> 4;
    const int t2 = w >> 1, h = w & 1;       // sampling: tap-in-round, ch-half
    const int ob = w & 3, pt = w >> 2;      // MFMA: o-block, p-block
    const int kh = l >> 5, c31 = l & 31;    // MFMA lane coords
    const int tp = l;                       // cube column
    const int cz = tp >> 4, cy = (tp >> 2) & 3, cx = tp & 3;
    const int zoA = Z4 + cz, yoA = Y4 + cy, xoA = X4 + cx;

    f32x16 acc;
#pragma unroll
    for (int i = 0; i < 16; ++i) acc[i] = 0.f;

#pragma unroll 1
    for (int g = 0; g < 8; ++g) {
        // (no top-of-g barrier: regB free after r=6 post-sample barrier;
        //  dbuf1/offls free after r=5 MFMA which precedes it in prog order)

        // ---- region staging: interleaved (hf = c&1), parity-swizzled ----
#pragma unroll 1
        for (int c = tid; c < 1800; c += 512) {
            const int hf = c & 1;
            const int v = c >> 1;
            const int zz = v / 100, r2 = v - zz * 100;
            const int yy = r2 / 10, xx = r2 - yy * 10;
            const int vz = min(max(Z4 - 3 + zz, 0), DD - 1);
            const int vy = min(max(Y4 - 3 + yy, 0), DH - 1);
            const int vx = min(max(X4 - 3 + xx, 0), DW - 1);
            const float4 val =
                up4[(size_t)((b * GG + g) * 2 + hf) * PP +
                    (vz << 10) + (vy << 5) + vx];
            const int sw = (xx + yy + zz + hf) & 1;      // parity swizzle
            *(float4*)(regB + v * 32 + sw * 16) = val;
        }

        // ---- phase A: offset mini-GEMM, A reused across all 4 ps ----
        if (w < 6) {
            f32x4 a[4];
#pragma unroll
            for (int ps = 0; ps < 4; ++ps) a[ps] = (f32x4){0.f, 0.f, 0.f, 0.f};
            __builtin_amdgcn_s_setprio(1);
#pragma unroll
            for (int c0 = 0; c0 < 8; ++c0) {
                const half8 A =
                    woxg[(size_t)((((g * 8 + c0) * 6 + w) * 16 + lo) * 4 + q)];
#pragma unroll
                for (int ps = 0; ps < 4; ++ps) {
                    const half8 B = catx[(c0 * 4 + q) * 64 + ps * 16 + lo];
                    a[ps] = __builtin_amdgcn_mfma_f32_16x16x32_f16(A, B, a[ps], 0, 0, 0);
                }
            }
            __builtin_amdgcn_s_setprio(0);
#pragma unroll
            for (int ps = 0; ps < 4; ++ps) {
#pragma unroll
                for (int r = 0; r < 4; ++r) {
                    const int m = w * 16 + q * 4 + r;
                    if (m < 81)
                        offls[m * OSTR + ps * 16 + lo] = (_Float16)a[ps][r];
                }
            }
        }
        __syncthreads();    // staging + offls complete

        // ---- offsets -> registers (reads ordered vs r=1 write by r=0 bar) ----
        float offv[7][3];
#pragma unroll
        for (int r = 0; r < 7; ++r) {
            const int tap = r * 4 + t2;
            if (tap < K3) {
#pragma unroll
                for (int c = 0; c < 3; ++c)
                    offv[r][c] = (float)offls[(tap * 3 + c) * OSTR + tp];
            }
        }
        // (no post-offv barrier: r=0 writes dbuf0, disjoint from offls)

        // ---- 7 rounds x (sample 4 taps -> A-prefetch -> barrier -> MFMA) ----
#pragma unroll
        for (int r = 0; r < 7; ++r) {
            half8* dbuf = sampx + (r & 1) * 544;
            const int tap = r * 4 + t2;
            if (tap < K3) {
                const int kz = tap / 9 - 1;
                const int ky = (tap / 3) % 3 - 1;
                const int kx = (tap % 3) - 1;
                const float z = (float)(zoA + kz) + offv[r][0];
                const float y = (float)(yoA + ky) + offv[r][1];
                const float x = (float)(xoA + kx) + offv[r][2];
                const float zf = floorf(z), yf = floorf(y), xf = floorf(x);
                const float fz = z - zf, fy = y - yf, fx = x - xf;
                const int z0i = (int)zf, y0i = (int)yf, x0i = (int)xf;

                const float wz0 = ((unsigned)z0i < DD) ? 1.f - fz : 0.f;
                const float wz1 = ((unsigned)(z0i + 1) < DD) ? fz : 0.f;
                const float wy0 = ((unsigned)y0i < DH) ? 1.f - fy : 0.f;
                const float wy1 = ((unsigned)(y0i + 1) < DH) ? fy : 0.f;
                const float wx0 = ((unsigned)x0i < DW) ? 1.f - fx : 0.f;
                const float wx1 = ((unsigned)(x0i + 1) < DW) ? fx : 0.f;
                float wcs[8];
                wcs[0] = wz0 * wy0 * wx0; wcs[1] = wz0 * wy0 * wx1;
                wcs[2] = wz0 * wy1 * wx0; wcs[3] = wz0 * wy1 * wx1;
                wcs[4] = wz1 * wy0 * wx0; wcs[5] = wz1 * wy0 * wx1;
                wcs[6] = wz1 * wy1 * wx0; wcs[7] = wz1 * wy1 * wx1;

                const int sz0 = z0i - (Z4 - 3);
                const int sy0 = y0i - (Y4 - 3);
                const int sx0 = x0i - (X4 - 3);

                __align__(16) __half2 acch[4];
#pragma unroll
                for (int rr = 0; rr < 4; ++rr) acch[rr] = __floats2half2_rn(0.f, 0.f);

                if ((unsigned)sz0 <= 7u && (unsigned)sy0 <= 8u &&
                    (unsigned)sx0 <= 8u) {
                    // LDS region gather, parity-swizzled half placement
                    const int v000 = (sz0 * 10 + sy0) * 10 + sx0;
                    const int s0 = (sx0 + sy0 + sz0 + h) & 1;   // base parity
                    const int s1 = s0 ^ 1;
                    const int vox[8] = {v000,       v000 + 1,
                                        v000 + 10,  v000 + 11,
                                        v000 + 100, v000 + 101,
                                        v000 + 110, v000 + 111};
                    const int sws[8] = {s0, s1, s1, s0, s1, s0, s0, s1};
                    half8 hv[8];
#pragma unroll
                    for (int ci = 0; ci < 8; ++ci)
                        hv[ci] = *(const half8*)(regB + vox[ci] * 32 + sws[ci] * 16);
#pragma unroll
                    for (int ci = 0; ci < 8; ++ci) {
                        const __half2 wh = __float2half2_rn(wcs[ci]);
                        const __half2* h2 = (const __half2*)&hv[ci];
#pragma unroll
                        for (int rr = 0; rr < 4; ++rr)
                            acch[rr] = __hfma2(h2[rr], wh, acch[rr]);
                    }
                } else {
                    // exact global fallback (rare)
                    const int iz0 = min(max(z0i, 0), DD - 1);
                    const int iz1 = min(max(z0i + 1, 0), DD - 1);
                    const int iy0 = min(max(y0i, 0), DH - 1);
                    const int iy1 = min(max(y0i + 1, 0), DH - 1);
                    const int ix0 = min(max(x0i, 0), DW - 1);
                    const int ix1 = min(max(x0i + 1, 0), DW - 1);
                    const int v000 = (iz0 << 10) + (iy0 << 5) + ix0;
                    const int dzo = (iz1 - iz0) << 10;
                    const int dyo = (iy1 - iy0) << 5;
                    const int dxo = ix1 - ix0;
                    const int vox[8] = {v000,             v000 + dxo,
                                        v000 + dyo,       v000 + dyo + dxo,
                                        v000 + dzo,       v000 + dzo + dxo,
                                        v000 + dzo + dyo, v000 + dzo + dyo + dxo};
                    const float4* baseF =
                        up4 + (size_t)((b * GG + g) * 2 + h) * PP;
#pragma unroll
                    for (int ci = 0; ci < 8; ++ci) {
                        const float4 u = baseF[vox[ci]];
                        const __half2 wh = __float2half2_rn(wcs[ci]);
                        const __half2* h2 = (const __half2*)&u;
#pragma unroll
                        for (int rr = 0; rr < 4; ++rr)
                            acch[rr] = __hfma2(h2[rr], wh, acch[rr]);
                    }
                }
                dbuf[(t2 * 2 + h) * SROW + tp + (tp >> 4)] = *(half8*)&acch[0];
            }

            // ---- A-prefetch for this round's MFMA: latency drains in barrier
            half8 Apre[4];
#pragma unroll
            for (int m = 0; m < 4; ++m)
                if (r * 4 + m < K3)
                    Apre[m] = wtx2[(size_t)((((g * 7 + r) * 4 + m) * 4 + ob) * 64 + l)];
            __syncthreads();

            // ---- MFMA: 32x32x16, wave tile 32o x 32p; 4 K-slices/round ----
            __builtin_amdgcn_s_setprio(1);
#pragma unroll
            for (int m = 0; m < 4; ++m) {
                if (r * 4 + m < K3) {
                    const int colg = pt * 32 + c31;
                    const half8 B = dbuf[(m * 2 + kh) * SROW + colg + (colg >> 4)];
                    acc = __builtin_amdgcn_mfma_f32_32x32x16_f16(Apre[m], B, acc, 0, 0, 0);
                }
            }
            __builtin_amdgcn_s_setprio(0);
        }
    }

    // ---- epilogue: ReLU + store (32x32 C/D layout) ----
    {
        const int cg = pt * 32 + c31;
        const int paddr = ((Z4 + (cg >> 4)) << 10) +
                          ((Y4 + ((cg >> 2) & 3)) << 5) + (X4 + (cg & 3));
#pragma unroll
        for (int reg = 0; reg < 16; ++reg) {
            const int row = (reg & 3) + 8 * (reg >> 2) + 4 * kh;
            const int o = ob * 32 + row;
            out[((size_t)(b * CDN + o) << 14) + paddr] = fmaxf(acc[reg], 0.f);
        }
    }
}

// ---------------------------------------------------------------------------
extern "C" void kernel_launch(void* const* d_in, const int* in_sizes, int n_in,
                              void* d_out, int out_size, void* d_ws, size_t ws_size,
                              hipStream_t stream)
{
    const float* src1x = (const float*)d_in[0];   // [2,128,8,16,16]
    const float* dst2x = (const float*)d_in[1];   // [2,128,16,32,32]
    const float* w_off = (const float*)d_in[2];   // [648,256]
    const float* w_dcn = (const float*)d_in[3];   // [128,128,3,3,3]
    float* out = (float*)d_out;

    char* ws = (char*)d_ws;
    half8* uph8 = (half8*)(ws);                    // 8,388,608 B
    half8* woxg = (half8*)(ws + 8388608);          //   393,216 B
    half8* wtx2 = (half8*)(ws + 8781824);          //   917,504 B

    prep_kernel<<<dim3(832), dim3(256), 0, stream>>>(
        src1x, w_off, w_dcn, uph8, woxg, wtx2);
    mega_kernel<<<dim3(256, BB), dim3(512), 0, stream>>>(
        dst2x, (const float4*)uph8, woxg, wtx2, out);
}